// Round 2
// baseline (1062.744 us; speedup 1.0000x reference)
//
#include <hip/hip_runtime.h>
#include <cstdint>

// ---------------------------------------------------------------------------
// WindowAttention: pad 96->100, roll(+2,+2), 4x4 windows, MHA(8 heads,d=64),
// unroll, crop. Token m = g*10000 + hh*100 + ww over padded rolled grid.
// Pipeline: gather -> qkv GEMM (8-phase 256^2) -> window attn -> out GEMM
// (8-phase 256^2, transposed, fused scatter epilogue).
// ---------------------------------------------------------------------------

typedef __attribute__((ext_vector_type(8))) __bf16 bf16x8;
typedef __attribute__((ext_vector_type(8))) uint16_t u16x8;
typedef __attribute__((ext_vector_type(4))) float f32x4;

__device__ __forceinline__ uint16_t f2bf(float f) {
  union { float f; uint32_t u; } c; c.f = f;
  uint32_t r = c.u + 0x7FFFu + ((c.u >> 16) & 1u);  // RNE
  return (uint16_t)(r >> 16);
}
__device__ __forceinline__ float bf2f(uint16_t u) {
  union { uint32_t u; float f; } c; c.u = ((uint32_t)u) << 16;
  return c.f;
}

__device__ __forceinline__ void g2lds16(const void* g, void* lds) {
  __builtin_amdgcn_global_load_lds(
      (const __attribute__((address_space(1))) uint32_t*)(uintptr_t)g,
      (__attribute__((address_space(3))) uint32_t*)(uintptr_t)lds,
      16, 0, 0);
}

#define CFENCE asm volatile("" ::: "memory")
#define BAR do { CFENCE; __builtin_amdgcn_s_barrier(); CFENCE; } while (0)

// ---------------------------------------------------------------------------
__global__ void cvt_weights(const float* __restrict__ w1, const float* __restrict__ w2,
                            uint16_t* __restrict__ o1, uint16_t* __restrict__ o2) {
  int i = blockIdx.x * 256 + threadIdx.x;
  if (i < 786432) o1[i] = f2bf(w1[i]);
  if (i < 262144) o2[i] = f2bf(w2[i]);
}

// ---------------------------------------------------------------------------
// Gather: x (NCHW fp32) -> token-major bf16 X[m,512]; pad+roll folded in.
// ---------------------------------------------------------------------------
__global__ __launch_bounds__(256) void gather_kernel(
    const float* __restrict__ x, uint16_t* __restrict__ xbf, int n0) {
  __shared__ float tile[64][65];
  const int z = blockIdx.z;
  const int g = z / 100, hh = z % 100;
  const int c0 = blockIdx.y * 64, ww0 = blockIdx.x * 64;
  const int n = n0 + g;
  const int hp = (hh >= 2) ? hh - 2 : hh + 98;
  const bool hok = hp < 96;
  const int t = threadIdx.x;
  const int lane = t & 63, grp = t >> 6;

  const int ww = ww0 + lane;
  const int wp = (ww >= 2) ? ww - 2 : ww + 98;
  const bool wok = hok && (ww < 100) && (wp < 96);
  const float* xb = x + ((size_t)n * 512) * 9216 + (size_t)hp * 96 + wp;
#pragma unroll
  for (int i = 0; i < 16; ++i) {
    int c = grp + i * 4;
    tile[c][lane] = wok ? xb[(size_t)(c0 + c) * 9216] : 0.f;
  }
  __syncthreads();
#pragma unroll
  for (int i = 0; i < 16; ++i) {
    int wl = grp + i * 4;
    int www = ww0 + wl;
    if (www < 100) {
      int m = g * 10000 + hh * 100 + www;
      xbf[(size_t)m * 512 + c0 + lane] = f2bf(tile[lane][wl]);
    }
  }
}

// ---------------------------------------------------------------------------
// 8-phase 256x256 GEMM, BK=64, K=512 fixed, 512 thr (8 waves 2Mx4N).
// D[row,col] = sum_k A[row,k]*B[col,k]; both row-major, stride 512.
// LDS 128KB: A tiles [2][256][64] then B tiles [2][256][64], XOR-swizzled
// (byte ^= (row&7)<<4) via pre-swizzled global source + swizzled ds_read.
// Schedule per K-tile quad (4 phases):
//   p0: ds_read a_lo/b_lo (12xb128) | stage (j+1,B-lo) | BAR | 16 MFMA | BAR
//   p1: ds_read a_hi/b_hi (12)      | stage (j+1,B-hi) | BAR | 16 MFMA | BAR
//   p2:                               stage (j+2,A-lo) | BAR | 16 MFMA | BAR
//   p3:  stage (j+2,A-hi) | vmcnt(4 or 0) | BAR | 16 MFMA | BAR
// All LDS reads of buf[cur] complete by p1's closing barrier, so p2/p3
// staging into buf[cur] is safe; vmcnt(4) leaves exactly the 2 newest
// half-tiles (next+1 A-halves) in flight.
// EPI 0: qkv epilogue (bf16, +bias[col]); EPI 1: out scatter (fp32, crop).
// MODE 0: bm=wg/NB, bn=wg%NB;  MODE 1: bm=wg%NB, bn=wg/NB.
// ---------------------------------------------------------------------------
template <int EPI, int NB, int MODE>
__global__ __launch_bounds__(512, 2) void gemm8(
    const uint16_t* __restrict__ A, const uint16_t* __restrict__ B,
    const float* __restrict__ bias, uint16_t* __restrict__ Cbf,
    float* __restrict__ Cout, int Mg, int n0) {
  __shared__ alignas(16) uint16_t lds[65536];  // 128 KB
  const int t = threadIdx.x;
  const int w = t >> 6, lane = t & 63;
  const int wr = w >> 2, wc = w & 3;
  const int lr = lane & 15, lg = lane >> 4;

  // bijective XCD swizzle (m204)
  const int nwg = gridDim.x, bid = blockIdx.x;
  const int q = nwg >> 3, r = nwg & 7;
  const int xc = bid & 7, li = bid >> 3;
  const int wg = (xc < r ? xc * (q + 1) : r * (q + 1) + (xc - r) * q) + li;
  int bm, bn;
  if (MODE == 0) { bm = wg / NB; bn = wg % NB; }
  else           { bm = wg % NB; bn = wg / NB; }

  // stage one half-tile: h 0=A-lo 1=A-hi 2=B-lo 3=B-hi (16KB, 2 loads/thr)
  auto STAGE = [&](int kt, int h) {
    const uint16_t* src = (h < 2) ? A : B;
    const int row0 = ((h < 2) ? bm * 256 : bn * 256) + (h & 1) * 128;
    const int base = ((h < 2) ? 0 : 32768) + (kt & 1) * 16384 + (h & 1) * 8192;
#pragma unroll
    for (int i = 0; i < 2; ++i) {
      int e = i * 512 + t;
      int row = e >> 3, slot = e & 7;
      const uint16_t* g = src + (size_t)(row0 + row) * 512 + kt * 64 +
                          ((slot ^ (row & 7)) << 3);
      g2lds16(g, &lds[base + ((i * 512 + w * 64) << 3)]);
    }
  };
  auto LDA = [&](int cur, int mi, int k2) -> bf16x8 {
    int row = wr * 128 + mi * 16 + lr;
    int byte = cur * 32768 + row * 128 + (((k2 * 32 + lg * 8) * 2) ^ ((row & 7) << 4));
    return *(const bf16x8*)((const char*)lds + byte);
  };
  auto LDB = [&](int cur, int ni, int k2) -> bf16x8 {
    int row = wc * 64 + ni * 16 + lr;
    int byte = 65536 + cur * 32768 + row * 128 +
               (((k2 * 32 + lg * 8) * 2) ^ ((row & 7) << 4));
    return *(const bf16x8*)((const char*)lds + byte);
  };

  f32x4 acc[8][4];
#pragma unroll
  for (int mi = 0; mi < 8; ++mi)
#pragma unroll
    for (int ni = 0; ni < 4; ++ni) acc[mi][ni] = (f32x4){0.f, 0.f, 0.f, 0.f};

  // prologue: K0 all 4 halves + K1 A-halves; vmcnt(4) -> K0 landed
  STAGE(0, 0); STAGE(0, 1); STAGE(0, 2); STAGE(0, 3);
  STAGE(1, 0); STAGE(1, 1);
  asm volatile("s_waitcnt vmcnt(4)" ::: "memory");
  BAR;

#define MFMAQ(AF, BF, MIOFF, NIOFF)                                        \
  __builtin_amdgcn_s_setprio(1);                                           \
  _Pragma("unroll") for (int mi = 0; mi < 4; ++mi)                         \
  _Pragma("unroll") for (int ni = 0; ni < 2; ++ni)                         \
  _Pragma("unroll") for (int k2 = 0; k2 < 2; ++k2)                         \
      acc[mi + MIOFF][ni + NIOFF] = __builtin_amdgcn_mfma_f32_16x16x32_bf16( \
          AF[mi][k2], BF[ni][k2], acc[mi + MIOFF][ni + NIOFF], 0, 0, 0);   \
  __builtin_amdgcn_s_setprio(0);

  for (int j = 0; j < 8; ++j) {
    const int cur = j & 1;
    bf16x8 a0[4][2], a1[4][2], b0[2][2], b1[2][2];
    // ---- phase 0: load lo frags, stage (j+1, B-lo)
#pragma unroll
    for (int mi = 0; mi < 4; ++mi)
#pragma unroll
      for (int k2 = 0; k2 < 2; ++k2) a0[mi][k2] = LDA(cur, mi, k2);
#pragma unroll
    for (int ni = 0; ni < 2; ++ni)
#pragma unroll
      for (int k2 = 0; k2 < 2; ++k2) b0[ni][k2] = LDB(cur, ni, k2);
    if (j + 1 < 8) STAGE(j + 1, 2);
    BAR;
    __builtin_amdgcn_sched_barrier(0);
    MFMAQ(a0, b0, 0, 0);
    BAR;
    // ---- phase 1: load hi frags, stage (j+1, B-hi)
#pragma unroll
    for (int mi = 0; mi < 4; ++mi)
#pragma unroll
      for (int k2 = 0; k2 < 2; ++k2) a1[mi][k2] = LDA(cur, mi + 4, k2);
#pragma unroll
    for (int ni = 0; ni < 2; ++ni)
#pragma unroll
      for (int k2 = 0; k2 < 2; ++k2) b1[ni][k2] = LDB(cur, ni + 2, k2);
    if (j + 1 < 8) STAGE(j + 1, 3);
    BAR;
    __builtin_amdgcn_sched_barrier(0);
    MFMAQ(a1, b1, 4, 2);
    BAR;
    // ---- phase 2: stage (j+2, A-lo)
    if (j + 2 < 8) STAGE(j + 2, 0);
    BAR;
    __builtin_amdgcn_sched_barrier(0);
    MFMAQ(a0, b1, 0, 2);
    BAR;
    // ---- phase 3: stage (j+2, A-hi), counted vmcnt
    if (j + 2 < 8) STAGE(j + 2, 1);
    if (j < 6) { asm volatile("s_waitcnt vmcnt(4)" ::: "memory"); }
    else       { asm volatile("s_waitcnt vmcnt(0)" ::: "memory"); }
    BAR;
    __builtin_amdgcn_sched_barrier(0);
    MFMAQ(a1, b0, 4, 0);
    BAR;
  }
#undef MFMAQ

  if (EPI == 0) {
#pragma unroll
    for (int ni = 0; ni < 4; ++ni) {
      int col = bn * 256 + wc * 64 + ni * 16 + lr;
      float bb = bias[col];
#pragma unroll
      for (int mi = 0; mi < 8; ++mi) {
        int row = bm * 256 + wr * 128 + mi * 16 + lg * 4;
#pragma unroll
        for (int rr = 0; rr < 4; ++rr)
          Cbf[(size_t)(row + rr) * 1536 + col] = f2bf(acc[mi][ni][rr] + bb);
      }
    }
  } else {
#pragma unroll
    for (int ni = 0; ni < 4; ++ni) {
      int tok = bn * 256 + wc * 64 + ni * 16 + lr;
      if (tok < Mg) {
        int g = tok / 10000, rem = tok % 10000;
        int hh = rem / 100, ww = rem % 100;
        if (hh >= 2 && hh < 98 && ww >= 2 && ww < 98) {
          size_t base = ((size_t)(n0 + g) * 512) * 9216 + (size_t)(hh - 2) * 96 + (ww - 2);
#pragma unroll
          for (int mi = 0; mi < 8; ++mi) {
            int c = bm * 256 + wr * 128 + mi * 16 + lg * 4;
#pragma unroll
            for (int rr = 0; rr < 4; ++rr)
              Cout[base + (size_t)(c + rr) * 9216] = acc[mi][ni][rr] + bias[c + rr];
          }
        }
      }
    }
  }
}

// ---------------------------------------------------------------------------
// Attention: 1 block/window, 128 thr = (head, query). fp32 VALU softmax.
// ---------------------------------------------------------------------------
__global__ __launch_bounds__(128) void attn_kernel(
    const uint16_t* __restrict__ qkv, const float* __restrict__ x,
    uint16_t* __restrict__ obuf, int n0) {
  __shared__ alignas(16) uint16_t sq[16][1536];
  __shared__ float smask[16];
  const int b = blockIdx.x;
  const int g = b / 625, wid = b % 625;
  const int ib = wid / 25, jb = wid % 25;
  const int t = threadIdx.x;
  const int mbase = g * 10000 + ib * 400 + jb * 4;

#pragma unroll
  for (int it = 0; it < 24; ++it) {
    int e = it * 128 + t;
    int l = e / 192;
    int off = (e - l * 192) * 8;
    int m = mbase + (l >> 2) * 100 + (l & 3);
    *(uint4*)&sq[l][off] = *(const uint4*)&qkv[(size_t)m * 1536 + off];
  }
  if (t < 16) {
    int hh = ib * 4 + (t >> 2), ww = jb * 4 + (t & 3);
    int a = (hh >= 4) ? hh - 4 : hh + 96;
    int c = (ww >= 4) ? ww - 4 : ww + 96;
    smask[t] = (a < 96 && c < 96)
                   ? x[((size_t)(n0 + g) * 512) * 9216 + (size_t)a * 96 + c]
                   : 0.f;
  }
  __syncthreads();

  const int h = t >> 4, qi = t & 15;
  float qv[64];
#pragma unroll
  for (int d8 = 0; d8 < 8; ++d8) {
    u16x8 v = *(const u16x8*)&sq[qi][h * 64 + d8 * 8];
#pragma unroll
    for (int j = 0; j < 8; ++j) qv[d8 * 8 + j] = bf2f(v[j]);
  }
  float s[16];
  float mx = -1e30f;
#pragma unroll
  for (int ki = 0; ki < 16; ++ki) {
    float a = 0.f;
#pragma unroll
    for (int d8 = 0; d8 < 8; ++d8) {
      u16x8 kv = *(const u16x8*)&sq[ki][512 + h * 64 + d8 * 8];
#pragma unroll
      for (int j = 0; j < 8; ++j) a += qv[d8 * 8 + j] * bf2f(kv[j]);
    }
    s[ki] = a * 0.125f + smask[ki];
    mx = fmaxf(mx, s[ki]);
  }
  float sum = 0.f;
#pragma unroll
  for (int ki = 0; ki < 16; ++ki) { s[ki] = __expf(s[ki] - mx); sum += s[ki]; }
  const float inv = 1.f / sum;
  float o[64];
#pragma unroll
  for (int d = 0; d < 64; ++d) o[d] = 0.f;
#pragma unroll
  for (int ki = 0; ki < 16; ++ki) {
    float wgt = s[ki] * inv;
#pragma unroll
    for (int d8 = 0; d8 < 8; ++d8) {
      u16x8 vv = *(const u16x8*)&sq[ki][1024 + h * 64 + d8 * 8];
#pragma unroll
      for (int j = 0; j < 8; ++j) o[d8 * 8 + j] += wgt * bf2f(vv[j]);
    }
  }
  const int m = mbase + (qi >> 2) * 100 + (qi & 3);
#pragma unroll
  for (int d8 = 0; d8 < 8; ++d8) {
    alignas(16) uint16_t tmp[8];
#pragma unroll
    for (int j = 0; j < 8; ++j) tmp[j] = f2bf(o[d8 * 8 + j]);
    *(uint4*)&obuf[(size_t)m * 512 + h * 64 + d8 * 8] = *(uint4*)tmp;
  }
}

// ---------------------------------------------------------------------------
extern "C" void kernel_launch(void* const* d_in, const int* in_sizes, int n_in,
                              void* d_out, int out_size, void* d_ws, size_t ws_size,
                              hipStream_t stream) {
  const float* x  = (const float*)d_in[0];
  const float* wq = (const float*)d_in[1];
  const float* bq = (const float*)d_in[2];
  const float* wo = (const float*)d_in[3];
  const float* bo = (const float*)d_in[4];
  float* out = (float*)d_out;
  uint8_t* ws = (uint8_t*)d_ws;

  uint16_t* wq_bf = (uint16_t*)ws;               // 1.5 MB
  uint16_t* wo_bf = (uint16_t*)(ws + 1572864);   // 0.5 MB
  uint8_t* bufbase = ws + 2097152;

  int G = 16;
  while (G > 1) {
    int Mg = G * 10000;
    int Mp = ((Mg + 255) / 256) * 256;
    size_t need = (size_t)2097152 + (size_t)Mp * 4096;
    if (need <= ws_size) break;
    G >>= 1;
  }
  const int Mg = G * 10000;
  const int Mp = ((Mg + 255) / 256) * 256;
  uint16_t* xo   = (uint16_t*)bufbase;                        // Mp*512 (X, then O)
  uint16_t* qkvb = (uint16_t*)(bufbase + (size_t)Mp * 1024);  // Mp*1536

  cvt_weights<<<dim3(3072), dim3(256), 0, stream>>>(wq, wo, wq_bf, wo_bf);

  for (int n0 = 0; n0 < 16; n0 += G) {
    gather_kernel<<<dim3(2, 8, G * 100), dim3(256), 0, stream>>>(x, xo, n0);
    // qkv[m,1536] = X @ Wqkv^T + b   (bm = token tiles, bn = 6 col tiles)
    gemm8<0, 6, 0><<<dim3((Mp / 256) * 6), dim3(512), 0, stream>>>(
        xo, wq_bf, bq, qkvb, nullptr, Mg, n0);
    attn_kernel<<<dim3(G * 625), dim3(128), 0, stream>>>(qkvb, x, xo, n0);
    // out^T[c,m] = Wout @ O^T + b, scattered (bm = 2 channel tiles, bn = token tiles)
    gemm8<1, 2, 1><<<dim3((Mp / 256) * 2), dim3(512), 0, stream>>>(
        wo_bf, xo, bo, nullptr, out, Mg, n0);
  }
  (void)in_sizes; (void)n_in; (void)out_size;
}